// Round 12
// baseline (314.816 us; speedup 1.0000x reference)
//
#include <hip/hip_runtime.h>
#include <math.h>

typedef __bf16 bf16_t;
typedef __bf16 bfrag8 __attribute__((ext_vector_type(8)));
typedef float  facc4  __attribute__((ext_vector_type(4)));
typedef float  f32x2  __attribute__((ext_vector_type(2)));

#define NBUCK 512   // dst-buckets for CSR multisplit (requires N < 65536 for 16-bit packing)
#define BCAP  4096  // per-bucket ebuf capacity (mean 1568, sd ~40)

__device__ inline unsigned short f2b(float x) {          // RNE float->bf16 bits
    unsigned int u = __float_as_uint(x);
    unsigned int r = (u + 0x7fffu + ((u >> 16) & 1u)) >> 16;
    return (unsigned short)r;
}
__device__ inline unsigned int pack2(float lo, float hi) {
    return (unsigned int)f2b(lo) | ((unsigned int)f2b(hi) << 16);
}
__device__ inline float blo(unsigned int q) { return __uint_as_float(q << 16); }
__device__ inline float bhi(unsigned int q) { return __uint_as_float(q & 0xffff0000u); }

// ---- fp8 e4m3 (OCP) encode/decode: HW cvt path with portable fallback ----
#if __has_builtin(__builtin_amdgcn_cvt_pk_f32_fp8) && __has_builtin(__builtin_amdgcn_cvt_pk_fp8_f32)
#define HW_FP8 1
#endif

__device__ inline f32x2 fp8pair_dec(unsigned short v) {
#ifdef HW_FP8
    return __builtin_amdgcn_cvt_pk_f32_fp8((int)(unsigned int)v, false);
#else
    f32x2 r;
    unsigned char b0 = (unsigned char)(v & 0xff), b1 = (unsigned char)(v >> 8);
    {
        int e = (b0 >> 3) & 0xf, m = b0 & 7;
        float mag = e ? ldexpf(8.f + m, e - 10) : ldexpf((float)m, -9);
        r.x = (b0 & 0x80) ? -mag : mag;
    }
    {
        int e = (b1 >> 3) & 0xf, m = b1 & 7;
        float mag = e ? ldexpf(8.f + m, e - 10) : ldexpf((float)m, -9);
        r.y = (b1 & 0x80) ? -mag : mag;
    }
    return r;
#endif
}
__device__ inline unsigned char fp8_enc(float x) {
#ifdef HW_FP8
    return (unsigned char)(__builtin_amdgcn_cvt_pk_fp8_f32(x, x, 0, false) & 0xff);
#else
    unsigned char s = (x < 0.f) ? 0x80 : 0;
    float ax = fabsf(x);
    if (!(ax > 0.f)) return s;
    if (ax >= 448.f) return s | 0x7e;
    if (ax < 0.015625f) {
        int q = (int)rintf(ax * 512.f);
        return s | (unsigned char)q;
    }
    int e; float m = frexpf(ax, &e);
    int q = (int)rintf(m * 16.f);
    int E = e - 1;
    if (q == 16) { q = 8; ++E; }
    if (E > 8) return s | 0x7e;
    return s | (unsigned char)(((E + 7) << 3) | (q - 8));
#endif
}

__device__ inline int bucket_of(int d, int N) {
    return (int)(((long long)d * NBUCK) / N);
}

// ---------------- fused prep + CSR multisplit pass 1 (one graph node) ----------
__global__ __launch_bounds__(256) void k_prepbin(const int* __restrict__ src,
                                                 const int* __restrict__ dst,
                                                 int* __restrict__ bcnt,
                                                 unsigned int* __restrict__ ebuf,
                                                 int E, int N,
                                                 const float* __restrict__ bert,
                                                 unsigned int* __restrict__ bertb, int n8,
                                                 const float* __restrict__ W1,
                                                 unsigned short* __restrict__ w1t,
                                                 const float* __restrict__ W2,
                                                 unsigned short* __restrict__ w2t,
                                                 const float* __restrict__ Wf,
                                                 unsigned short* __restrict__ fwt) {
    __shared__ __align__(16) unsigned char smem[23552];
    int bb = blockIdx.x, tid = threadIdx.x;
    int nbin = (E + 4095) / 4096;
    if (bb < nbin) {   // ---- multisplit chunk of 4096 edges into NBUCK regions
        unsigned int* sorted = (unsigned int*)smem;            // 16384 B
        int* hist   = (int*)(smem + 16384);                    // 2048 B
        int* lstart = (int*)(smem + 18432);                    // 2048 B
        int* gbase  = (int*)(smem + 20480);                    // 2048 B
        int* sm     = (int*)(smem + 22528);                    // 1024 B
        int base = bb * 4096;
        int cnt = min(4096, E - base);
        hist[tid] = 0; hist[tid + 256] = 0;
        __syncthreads();
        unsigned int mye[16]; int myb[16];
#pragma unroll
        for (int i = 0; i < 16; ++i) {
            int idx = i * 256 + tid;
            myb[i] = -1;
            if (idx < cnt) {
                int e = base + idx;
                int s = src[e], d = dst[e];
                mye[i] = ((unsigned int)s << 16) | (unsigned int)d;   // needs s,d < 65536
                int b = bucket_of(d, N);
                myb[i] = b;
                atomicAdd(&hist[b], 1);
            }
        }
        __syncthreads();
        int p0 = hist[2 * tid], p1 = hist[2 * tid + 1];
        sm[tid] = p0 + p1;
        __syncthreads();
        for (int off = 1; off < 256; off <<= 1) {
            int x = (tid >= off) ? sm[tid - off] : 0;
            __syncthreads();
            sm[tid] += x;
            __syncthreads();
        }
        int excl = sm[tid] - (p0 + p1);
        lstart[2 * tid] = excl;
        lstart[2 * tid + 1] = excl + p0;
        __syncthreads();
        hist[tid] = lstart[tid]; hist[tid + 256] = lstart[tid + 256];
        __syncthreads();
#pragma unroll
        for (int i = 0; i < 16; ++i) {
            if (myb[i] >= 0) {
                int pos = atomicAdd(&hist[myb[i]], 1);
                sorted[pos] = mye[i];
            }
        }
        __syncthreads();
        for (int b = tid; b < NBUCK; b += 256) {
            int c = hist[b] - lstart[b];
            gbase[b] = (c > 0) ? atomicAdd(&bcnt[b], c) : 0;
        }
        __syncthreads();
        for (int idx = tid; idx < cnt; idx += 256) {
            unsigned int v = sorted[idx];
            int b = bucket_of((int)(v & 0xffffu), N);
            ebuf[(size_t)b * BCAP + gbase[b] + (idx - lstart[b])] = v;
        }
        return;
    }
    bb -= nbin;
    int ncvt = (n8 + 255) / 256;
    if (bb < ncvt) {   // ---- bert fp32 -> bf16
        int i = bb * 256 + tid;
        if (i >= n8) return;
        const float4* p = (const float4*)bert + (size_t)i * 2;
        float4 a = p[0], b = p[1];
        uint4 o;
        o.x = pack2(a.x, a.y);
        o.y = pack2(a.z, a.w);
        o.z = pack2(b.x, b.y);
        o.w = pack2(b.z, b.w);
        ((uint4*)bertb)[i] = o;
        return;
    }
    bb -= ncvt;
    if (bb < 128) {    // ---- W1/W2 transpose (64KB each)
        int i = bb * 256 + tid;
        const float* W = (i < 16384) ? W1 : W2;
        unsigned short* Wt = (i < 16384) ? w1t : w2t;
        int idx = i & 16383;
        int n = idx >> 7, k = idx & 127;
        Wt[idx] = f2b(W[k * 128 + n]);
        return;
    }
    bb -= 128;
    {                  // ---- fc1w tiled transpose, 7 x 14 = 98 blocks
        float* tile = (float*)smem;    // 64 x 65 floats = 16640 B
        int n0 = (bb % 7) * 64, k0 = (bb / 7) * 64;
#pragma unroll
        for (int i = 0; i < 16; ++i) {
            int idx = i * 256 + tid;
            int r = idx >> 6, c = idx & 63;
            tile[r * 65 + c] = Wf[(size_t)(k0 + r) * 448 + n0 + c];
        }
        __syncthreads();
#pragma unroll
        for (int i = 0; i < 16; ++i) {
            int idx = i * 256 + tid;
            int c = idx >> 6, r = idx & 63;
            fwt[(size_t)(n0 + c) * 896 + k0 + r] = f2b(tile[r * 65 + c]);
        }
    }
}

// ---------------- CSR pass 2: per-bucket build; bucket base via inline reduction.
__global__ __launch_bounds__(256) void k_build2(const unsigned int* __restrict__ ebuf,
                                                const int* __restrict__ bcnt,
                                                int* __restrict__ offs,
                                                float* __restrict__ dinv,
                                                unsigned short* __restrict__ csr,
                                                int N, int E) {
    __shared__ unsigned short seg[BCAP];
    __shared__ int cnt_l[128];
    __shared__ int scan_l[128];
    __shared__ int curs[128];
    __shared__ int smr[256];
    int b = blockIdx.x, tid = threadIdx.x;
    int part = 0;
    for (int j = tid; j < b; j += 256) part += bcnt[j];
    smr[tid] = part;
    __syncthreads();
    for (int off = 128; off > 0; off >>= 1) {
        if (tid < off) smr[tid] += smr[tid + off];
        __syncthreads();
    }
    int base = smr[0];
    int lo = (int)(((long long)b * N + NBUCK - 1) / NBUCK);
    int cnt = bcnt[b];
    int nrange = (int)(((long long)(b + 1) * N + NBUCK - 1) / NBUCK) - lo;   // <= 98
    if (b == 0 && tid == 0) offs[N] = E;
    if (tid < 128) cnt_l[tid] = 0;
    __syncthreads();
    for (int i = tid; i < cnt; i += 256) {
        unsigned int v = ebuf[(size_t)b * BCAP + i];
        atomicAdd(&cnt_l[(int)(v & 0xffffu) - lo], 1);
    }
    __syncthreads();
    if (tid < 128) scan_l[tid] = cnt_l[tid];
    __syncthreads();
    for (int off = 1; off < 128; off <<= 1) {
        int x = 0;
        if (tid < 128 && tid >= off) x = scan_l[tid - off];
        __syncthreads();
        if (tid < 128) scan_l[tid] += x;
        __syncthreads();
    }
    if (tid < 128) {
        int excl = scan_l[tid] - cnt_l[tid];
        curs[tid] = excl;
        if (tid < nrange) {
            offs[lo + tid] = base + excl;
            dinv[lo + tid] = rsqrtf((float)(cnt_l[tid] + 1));   // +1 = self loop
        }
    }
    __syncthreads();
    for (int i = tid; i < cnt; i += 256) {
        unsigned int v = ebuf[(size_t)b * BCAP + i];
        int d = (int)(v & 0xffffu) - lo;
        int p = atomicAdd(&curs[d], 1);
        seg[p] = (unsigned short)(v >> 16);
    }
    __syncthreads();
    for (int i = tid; i < cnt; i += 256) csr[base + i] = seg[i];
}

// ---------------- MFMA GEMM (fp32 A, inline cvt): out8 = fp8((A @ Bt^T) * rs) ----
__global__ __launch_bounds__(256) void k_gemm_f32a(const float* __restrict__ A,
                                                   const bf16_t* __restrict__ Bt,
                                                   const float* __restrict__ rs,
                                                   unsigned char* __restrict__ out8, int M) {
    __shared__ bf16_t As[64 * 136];
    __shared__ bf16_t Bs[128 * 136];
    int t = threadIdx.x;
    int wave = t >> 6, lane = t & 63, quad = lane >> 4, l16 = lane & 15;
    int r0 = blockIdx.x * 64;
#pragma unroll
    for (int i = 0; i < 4; ++i) {
        int chunk = t + i * 256;
        int row = chunk >> 4, c8 = (chunk & 15) << 3;
        int gr = r0 + row;
        float4 a0 = make_float4(0.f, 0.f, 0.f, 0.f), a1 = a0;
        if (gr < M) {
            a0 = *(const float4*)&A[(size_t)gr * 128 + c8];
            a1 = *(const float4*)&A[(size_t)gr * 128 + c8 + 4];
        }
        *(uint4*)&As[row * 136 + c8] =
            make_uint4(pack2(a0.x, a0.y), pack2(a0.z, a0.w),
                       pack2(a1.x, a1.y), pack2(a1.z, a1.w));
    }
#pragma unroll
    for (int i = 0; i < 8; ++i) {
        int chunk = t + i * 256;
        int row = chunk >> 4, c8 = (chunk & 15) << 3;
        *(uint4*)&Bs[row * 136 + c8] = *(const uint4*)&Bt[row * 128 + c8];
    }
    __syncthreads();

    facc4 acc[8];
#pragma unroll
    for (int nt = 0; nt < 8; ++nt) acc[nt] = (facc4){0.f, 0.f, 0.f, 0.f};
    int arow = (wave << 4) + l16;
#pragma unroll
    for (int ks = 0; ks < 4; ++ks) {
        int kk = ks * 32 + quad * 8;
        bfrag8 af = *(const bfrag8*)&As[arow * 136 + kk];
#pragma unroll
        for (int nt = 0; nt < 8; ++nt) {
            bfrag8 bf = *(const bfrag8*)&Bs[(nt * 16 + l16) * 136 + kk];
            acc[nt] = __builtin_amdgcn_mfma_f32_16x16x32_bf16(af, bf, acc[nt], 0, 0, 0);
        }
    }
    __syncthreads();
    unsigned char* f8t = (unsigned char*)As;   // 64*128 bytes
    int wrow0 = (wave << 4) + quad * 4;
#pragma unroll
    for (int r = 0; r < 4; ++r) {
        int row = wrow0 + r;
        float sc = rs[min(r0 + row, M - 1)];
#pragma unroll
        for (int nt = 0; nt < 8; ++nt)
            f8t[row * 128 + nt * 16 + l16] = fp8_enc(acc[nt][r] * sc);
    }
    __syncthreads();
#pragma unroll
    for (int i = 0; i < 2; ++i) {
        int idx = t + i * 256;              // 512 chunks of 16B
        int row = idx >> 3, cc = (idx & 7) << 4;
        int gr = r0 + row;
        if (gr < M) *(uint4*)&out8[(size_t)gr * 128 + cc] = *(const uint4*)&f8t[row * 128 + cc];
    }
}

// ---------------- MFMA GEMM (bf16 A): out8 = fp8((A @ Bt^T) * rs) ----------------
__global__ __launch_bounds__(256) void k_gemm_nn128(const bf16_t* __restrict__ A,
                                                    const bf16_t* __restrict__ Bt,
                                                    const float* __restrict__ rs,
                                                    unsigned char* __restrict__ out8, int M) {
    __shared__ bf16_t As[64 * 136];
    __shared__ bf16_t Bs[128 * 136];
    int t = threadIdx.x;
    int wave = t >> 6, lane = t & 63, quad = lane >> 4, l16 = lane & 15;
    int r0 = blockIdx.x * 64;
#pragma unroll
    for (int i = 0; i < 4; ++i) {
        int chunk = t + i * 256;
        int row = chunk >> 4, c8 = (chunk & 15) << 3;
        int gr = r0 + row;
        uint4 v = make_uint4(0u, 0u, 0u, 0u);
        if (gr < M) v = *(const uint4*)&A[(size_t)gr * 128 + c8];
        *(uint4*)&As[row * 136 + c8] = v;
    }
#pragma unroll
    for (int i = 0; i < 8; ++i) {
        int chunk = t + i * 256;
        int row = chunk >> 4, c8 = (chunk & 15) << 3;
        *(uint4*)&Bs[row * 136 + c8] = *(const uint4*)&Bt[row * 128 + c8];
    }
    __syncthreads();

    facc4 acc[8];
#pragma unroll
    for (int nt = 0; nt < 8; ++nt) acc[nt] = (facc4){0.f, 0.f, 0.f, 0.f};
    int arow = (wave << 4) + l16;
#pragma unroll
    for (int ks = 0; ks < 4; ++ks) {
        int kk = ks * 32 + quad * 8;
        bfrag8 af = *(const bfrag8*)&As[arow * 136 + kk];
#pragma unroll
        for (int nt = 0; nt < 8; ++nt) {
            bfrag8 bf = *(const bfrag8*)&Bs[(nt * 16 + l16) * 136 + kk];
            acc[nt] = __builtin_amdgcn_mfma_f32_16x16x32_bf16(af, bf, acc[nt], 0, 0, 0);
        }
    }
    __syncthreads();
    unsigned char* f8t = (unsigned char*)As;
    int wrow0 = (wave << 4) + quad * 4;
#pragma unroll
    for (int r = 0; r < 4; ++r) {
        int row = wrow0 + r;
        float sc = rs[min(r0 + row, M - 1)];
#pragma unroll
        for (int nt = 0; nt < 8; ++nt)
            f8t[row * 128 + nt * 16 + l16] = fp8_enc(acc[nt][r] * sc);
    }
    __syncthreads();
#pragma unroll
    for (int i = 0; i < 2; ++i) {
        int idx = t + i * 256;
        int row = idx >> 3, cc = (idx & 7) << 4;
        int gr = r0 + row;
        if (gr < M) *(uint4*)&out8[(size_t)gr * 128 + cc] = *(const uint4*)&f8t[row * 128 + cc];
    }
}

// ---------------- aggregation: wave per node, fp8 gather (128 B/row) ----------------
__global__ __launch_bounds__(256) void k_agg_b(const unsigned short* __restrict__ hx8, // [N][64]
                                               const unsigned short* __restrict__ csr,
                                               const int* __restrict__ offs,
                                               const float* __restrict__ dinv,
                                               const float* __restrict__ bias,
                                               unsigned int* __restrict__ out, int N) {
    int node = blockIdx.x * 4 + (threadIdx.x >> 6);
    int lane = threadIdx.x & 63;
    if (node >= N) return;
    float di = dinv[node];
    f32x2 sf = fp8pair_dec(hx8[(size_t)node * 64 + lane]);
    float acc0 = sf.x, acc1 = sf.y;                   // self term (already *dinv)
    int s0 = offs[node], s1 = offs[node + 1];
    for (int base = s0; base < s1; base += 64) {
        int nloc = min(64, s1 - base);
        int en = 0;
        if (lane < nloc) en = (int)csr[base + lane];
        int j = 0;
        for (; j + 16 <= nloc; j += 16) {
            int sid[16]; unsigned short g[16];
#pragma unroll
            for (int u = 0; u < 16; ++u) sid[u] = __shfl(en, j + u, 64);
#pragma unroll
            for (int u = 0; u < 16; ++u) g[u] = hx8[(size_t)sid[u] * 64 + lane];  // 16 in flight
#pragma unroll
            for (int u = 0; u < 16; ++u) { f32x2 d = fp8pair_dec(g[u]); acc0 += d.x; acc1 += d.y; }
        }
        for (; j + 4 <= nloc; j += 4) {
            int sid[4]; unsigned short g[4];
#pragma unroll
            for (int u = 0; u < 4; ++u) sid[u] = __shfl(en, j + u, 64);
#pragma unroll
            for (int u = 0; u < 4; ++u) g[u] = hx8[(size_t)sid[u] * 64 + lane];
#pragma unroll
            for (int u = 0; u < 4; ++u) { f32x2 d = fp8pair_dec(g[u]); acc0 += d.x; acc1 += d.y; }
        }
        for (; j < nloc; ++j) {
            int srcn = __shfl(en, j, 64);
            f32x2 d = fp8pair_dec(hx8[(size_t)srcn * 64 + lane]);
            acc0 += d.x; acc1 += d.y;
        }
    }
    float2 bb = *(const float2*)&bias[lane * 2];
    float v0 = fmaxf(acc0 * di + bb.x, 0.f);
    float v1 = fmaxf(acc1 * di + bb.y, 0.f);
    out[(size_t)node * 64 + lane] = pack2(v0, v1);
}

// ---------------- entity mean pool (bf16 in/out): wave per row ----------------
__global__ __launch_bounds__(256) void k_pool_b(const unsigned int* __restrict__ h,
                                                const int* __restrict__ ent,
                                                unsigned int* __restrict__ out) {
    int r = blockIdx.x * 4 + (threadIdx.x >> 6);
    int lane = threadIdx.x & 63;
    float a0 = 0.f, a1 = 0.f;
    int cnt = 0;
#pragma unroll
    for (int m = 0; m < 20; ++m) {
        int id = ent[r * 20 + m];
        if (id >= 0) {
            unsigned int q = h[(size_t)id * 64 + lane];
            a0 += blo(q); a1 += bhi(q); cnt++;
        }
    }
    float inv = 1.f / (float)max(cnt, 1);
    out[(size_t)r * 64 + lane] = pack2(a0 * inv, a1 * inv);
}

// ---------------- MLP fc1+fc2 fused (MFMA), 32x64 tiles + reg-prefetch pipeline,
//                  last-block sigmoid. grid (M/32, 7), block 128 = 2 waves. ------
__global__ __launch_bounds__(128) void k_mlp1_mfma(const bf16_t* __restrict__ bertb,
                                                   const bf16_t* __restrict__ gnnb,
                                                   const bf16_t* __restrict__ fwt,  // [448][896]
                                                   const float* __restrict__ fb,
                                                   const float* __restrict__ w2,   // fc2_w [448]
                                                   float* __restrict__ logacc,
                                                   int* __restrict__ donecnt,
                                                   const float* __restrict__ b2,   // fc2_b [1]
                                                   float* __restrict__ outp, int B) {
    __shared__ bf16_t As[32 * 136];
    __shared__ bf16_t Bs[64 * 136];
    __shared__ int lastflag;
    int t = threadIdx.x;                 // 0..127
    int wave = t >> 6, lane = t & 63, quad = lane >> 4, l16 = lane & 15;
    int r0 = blockIdx.x * 32, c0 = blockIdx.y * 64;
    facc4 acc[4];
#pragma unroll
    for (int nt = 0; nt < 4; ++nt) acc[nt] = (facc4){0.f, 0.f, 0.f, 0.f};

    uint4 pa[4], pb[8];
#define LOAD_A(ks) do { \
    _Pragma("unroll") \
    for (int i = 0; i < 4; ++i) { \
        int chunk = t + i * 128; \
        int row = chunk >> 4, c8 = (chunk & 15) << 3; \
        int gr = r0 + row; \
        const bf16_t* srcp = ((ks) < 6) ? &bertb[(size_t)gr * 768 + (ks) * 128 + c8] \
                                        : &gnnb[(size_t)gr * 128 + c8]; \
        pa[i] = *(const uint4*)srcp; \
    } } while (0)
#define LOAD_B(ks) do { \
    _Pragma("unroll") \
    for (int i = 0; i < 8; ++i) { \
        int chunk = t + i * 128; \
        int row = chunk >> 4, c8 = (chunk & 15) << 3; \
        pb[i] = *(const uint4*)&fwt[(size_t)(c0 + row) * 896 + (ks) * 128 + c8]; \
    } } while (0)
#define STORE_AB() do { \
    _Pragma("unroll") \
    for (int i = 0; i < 4; ++i) { \
        int chunk = t + i * 128; \
        int row = chunk >> 4, c8 = (chunk & 15) << 3; \
        *(uint4*)&As[row * 136 + c8] = pa[i]; \
    } \
    _Pragma("unroll") \
    for (int i = 0; i < 8; ++i) { \
        int chunk = t + i * 128; \
        int row = chunk >> 4, c8 = (chunk & 15) << 3; \
        *(uint4*)&Bs[row * 136 + c8] = pb[i]; \
    } } while (0)

    LOAD_A(0); LOAD_B(0);
    STORE_AB();
    __syncthreads();
    for (int ks = 0; ks < 7; ++ks) {
        if (ks < 6) { LOAD_A(ks + 1); LOAD_B(ks + 1); }   // prefetch into regs
        int arow = (wave << 4) + l16;
#pragma unroll
        for (int sub = 0; sub < 4; ++sub) {
            int kk = sub * 32 + quad * 8;
            bfrag8 af = *(const bfrag8*)&As[arow * 136 + kk];
#pragma unroll
            for (int nt = 0; nt < 4; ++nt) {
                bfrag8 bf = *(const bfrag8*)&Bs[(nt * 16 + l16) * 136 + kk];
                acc[nt] = __builtin_amdgcn_mfma_f32_16x16x32_bf16(af, bf, acc[nt], 0, 0, 0);
            }
        }
        __syncthreads();
        if (ks < 6) { STORE_AB(); __syncthreads(); }
    }
#undef LOAD_A
#undef LOAD_B
#undef STORE_AB
    // epilogue: bias+relu, dot with fc2w slice, reduce over the 16 col-lanes
    int rbase = r0 + (wave << 4) + quad * 4;
    float part[4] = {0.f, 0.f, 0.f, 0.f};
#pragma unroll
    for (int nt = 0; nt < 4; ++nt) {
        int col = c0 + nt * 16 + l16;
        float bb = fb[col];
        float ww = w2[col];
#pragma unroll
        for (int r = 0; r < 4; ++r)
            part[r] += fmaxf(acc[nt][r] + bb, 0.f) * ww;
    }
#pragma unroll
    for (int m = 8; m >= 1; m >>= 1) {
#pragma unroll
        for (int r = 0; r < 4; ++r) part[r] += __shfl_xor(part[r], m, 64);
    }
    if (l16 == 0) {
#pragma unroll
        for (int r = 0; r < 4; ++r) atomicAdd(&logacc[rbase + r], part[r]);
    }
    // completion-counter: last of the blocks applies bias+sigmoid
    __threadfence();
    __syncthreads();
    if (t == 0) {
        int done = atomicAdd(donecnt, 1);
        lastflag = (done == (int)(gridDim.x * gridDim.y) - 1);
    }
    __syncthreads();
    if (lastflag) {
        __threadfence();
        float bias2 = b2[0];
        for (int i = t; i < B; i += 128) {
            float v = atomicAdd(&logacc[i], 0.0f);    // coherent read
            outp[i] = 1.f / (1.f + expf(-(v + bias2)));
        }
    }
}

extern "C" void kernel_launch(void* const* d_in, const int* in_sizes, int n_in,
                              void* d_out, int out_size, void* d_ws, size_t ws_size,
                              hipStream_t stream) {
    const float* bert = (const float*)d_in[0];
    const float* x    = (const float*)d_in[1];
    const int*   ei   = (const int*)d_in[2];
    const int*   ent  = (const int*)d_in[3];
    const float* W1   = (const float*)d_in[4];
    const float* b1   = (const float*)d_in[5];
    const float* W2   = (const float*)d_in[6];
    const float* b2   = (const float*)d_in[7];
    const float* fc1w = (const float*)d_in[8];
    const float* fc1b = (const float*)d_in[9];
    const float* fc2w = (const float*)d_in[10];
    const float* fc2b = (const float*)d_in[11];
    float* out = (float*)d_out;

    const int N = in_sizes[1] / 128;   // 50000 (< 65536 required for 16-bit packing)
    const int E = in_sizes[2] / 2;     // 800000
    const int B = in_sizes[0] / 768;   // 4096

    const int* srcv = ei;
    const int* dstv = ei + E;

    char* wsp = (char*)d_ws;
    size_t off = 0;
    auto alloc = [&](size_t bytes) -> void* {
        void* p = wsp + off;
        off += (bytes + 255) & ~(size_t)255;
        return p;
    };
    // bcnt/logacc/donecnt contiguous -> one memset
    int*   bcnt   = (int*)alloc(NBUCK * 4);               // 2048
    float* logacc = (float*)alloc((size_t)B * 4);         // 16384
    int*   donecnt= (int*)alloc(4);                       // 256 (padded)
    float* dinv   = (float*)alloc((size_t)N * 4);
    int*   offs   = (int*)alloc((size_t)(N + 1) * 4);
    unsigned int*   ebuf  = (unsigned int*)alloc((size_t)NBUCK * BCAP * 4);   // 8 MB
    unsigned short* csr16 = (unsigned short*)alloc((size_t)E * 2);
    bf16_t* bertb = (bf16_t*)alloc((size_t)B * 768 * 2);
    bf16_t* w1t   = (bf16_t*)alloc(128 * 128 * 2);
    bf16_t* w2t   = (bf16_t*)alloc(128 * 128 * 2);
    bf16_t* fwt   = (bf16_t*)alloc((size_t)896 * 448 * 2);
    unsigned char* g8buf = (unsigned char*)alloc((size_t)N * 128);   // fp8 h' = (hW)*dinv
    bf16_t* hbuf  = (bf16_t*)alloc((size_t)N * 128 * 2);             // agg out (post-relu)
    bf16_t* gnnb  = (bf16_t*)alloc((size_t)B * 128 * 2);
    (void)ws_size; (void)n_in; (void)out_size;

    hipMemsetAsync(bcnt, 0, 2048 + 16384 + 256, stream);

    int nb8 = B * 768 / 8;
    int nbin = (E + 4095) / 4096;
    int nprep = nbin + (nb8 + 255) / 256 + 128 + 98;
    k_prepbin<<<nprep, 256, 0, stream>>>(srcv, dstv, bcnt, ebuf, E, N,
                                         bert, (unsigned int*)bertb, nb8,
                                         W1, (unsigned short*)w1t, W2, (unsigned short*)w2t,
                                         fc1w, (unsigned short*)fwt);
    k_build2<<<NBUCK, 256, 0, stream>>>(ebuf, bcnt, offs, dinv, csr16, N, E);

    int gb = (N + 63) / 64;
    k_gemm_f32a<<<gb, 256, 0, stream>>>(x, w1t, dinv, g8buf, N);
    k_agg_b<<<(N + 3) / 4, 256, 0, stream>>>((const unsigned short*)g8buf, csr16, offs, dinv, b1,
                                             (unsigned int*)hbuf, N);
    k_gemm_nn128<<<gb, 256, 0, stream>>>(hbuf, w2t, dinv, g8buf, N);
    k_agg_b<<<(N + 3) / 4, 256, 0, stream>>>((const unsigned short*)g8buf, csr16, offs, dinv, b2,
                                             (unsigned int*)hbuf, N);
    k_pool_b<<<B / 4, 256, 0, stream>>>((const unsigned int*)hbuf, ent, (unsigned int*)gnnb);
    k_mlp1_mfma<<<dim3(B / 32, 7), 128, 0, stream>>>(bertb, gnnb, fwt, fc1b, fc2w,
                                                     logacc, donecnt, fc2b, out, B);
}

// Round 13
// 237.370 us; speedup vs baseline: 1.3263x; 1.3263x over previous
//
#include <hip/hip_runtime.h>
#include <math.h>

typedef __bf16 bf16_t;
typedef __bf16 bfrag8 __attribute__((ext_vector_type(8)));
typedef float  facc4  __attribute__((ext_vector_type(4)));
typedef float  f32x2  __attribute__((ext_vector_type(2)));

#define NBUCK 512   // dst-buckets for CSR multisplit (requires N < 65536 for 16-bit packing)
#define BCAP  4096  // per-bucket ebuf capacity (mean 1568, sd ~40)

__device__ inline unsigned short f2b(float x) {          // RNE float->bf16 bits
    unsigned int u = __float_as_uint(x);
    unsigned int r = (u + 0x7fffu + ((u >> 16) & 1u)) >> 16;
    return (unsigned short)r;
}
__device__ inline unsigned int pack2(float lo, float hi) {
    return (unsigned int)f2b(lo) | ((unsigned int)f2b(hi) << 16);
}
__device__ inline float blo(unsigned int q) { return __uint_as_float(q << 16); }
__device__ inline float bhi(unsigned int q) { return __uint_as_float(q & 0xffff0000u); }

// ---- fp8 e4m3 (OCP) encode/decode: HW cvt path with portable fallback ----
#if __has_builtin(__builtin_amdgcn_cvt_pk_f32_fp8) && __has_builtin(__builtin_amdgcn_cvt_pk_fp8_f32)
#define HW_FP8 1
#endif

__device__ inline f32x2 fp8pair_dec(unsigned short v) {
#ifdef HW_FP8
    return __builtin_amdgcn_cvt_pk_f32_fp8((int)(unsigned int)v, false);
#else
    f32x2 r;
    unsigned char b0 = (unsigned char)(v & 0xff), b1 = (unsigned char)(v >> 8);
    {
        int e = (b0 >> 3) & 0xf, m = b0 & 7;
        float mag = e ? ldexpf(8.f + m, e - 10) : ldexpf((float)m, -9);
        r.x = (b0 & 0x80) ? -mag : mag;
    }
    {
        int e = (b1 >> 3) & 0xf, m = b1 & 7;
        float mag = e ? ldexpf(8.f + m, e - 10) : ldexpf((float)m, -9);
        r.y = (b1 & 0x80) ? -mag : mag;
    }
    return r;
#endif
}
__device__ inline unsigned char fp8_enc(float x) {
#ifdef HW_FP8
    return (unsigned char)(__builtin_amdgcn_cvt_pk_fp8_f32(x, x, 0, false) & 0xff);
#else
    unsigned char s = (x < 0.f) ? 0x80 : 0;
    float ax = fabsf(x);
    if (!(ax > 0.f)) return s;
    if (ax >= 448.f) return s | 0x7e;
    if (ax < 0.015625f) {
        int q = (int)rintf(ax * 512.f);
        return s | (unsigned char)q;
    }
    int e; float m = frexpf(ax, &e);
    int q = (int)rintf(m * 16.f);
    int E = e - 1;
    if (q == 16) { q = 8; ++E; }
    if (E > 8) return s | 0x7e;
    return s | (unsigned char)(((E + 7) << 3) | (q - 8));
#endif
}

__device__ inline int bucket_of(int d, int N) {
    return (int)(((long long)d * NBUCK) / N);
}

// ---------------- fused prep + CSR multisplit pass 1 (one graph node) ----------
__global__ __launch_bounds__(256) void k_prepbin(const int* __restrict__ src,
                                                 const int* __restrict__ dst,
                                                 int* __restrict__ bcnt,
                                                 unsigned int* __restrict__ ebuf,
                                                 int E, int N,
                                                 const float* __restrict__ W1,
                                                 unsigned short* __restrict__ w1t,
                                                 const float* __restrict__ W2,
                                                 unsigned short* __restrict__ w2t,
                                                 const float* __restrict__ Wf,
                                                 unsigned short* __restrict__ fwt) {
    __shared__ __align__(16) unsigned char smem[23552];
    int bb = blockIdx.x, tid = threadIdx.x;
    int nbin = (E + 4095) / 4096;
    if (bb < nbin) {   // ---- multisplit chunk of 4096 edges into NBUCK regions
        unsigned int* sorted = (unsigned int*)smem;            // 16384 B
        int* hist   = (int*)(smem + 16384);                    // 2048 B
        int* lstart = (int*)(smem + 18432);                    // 2048 B
        int* gbase  = (int*)(smem + 20480);                    // 2048 B
        int* sm     = (int*)(smem + 22528);                    // 1024 B
        int base = bb * 4096;
        int cnt = min(4096, E - base);
        hist[tid] = 0; hist[tid + 256] = 0;
        __syncthreads();
        unsigned int mye[16]; int myb[16];
#pragma unroll
        for (int i = 0; i < 16; ++i) {
            int idx = i * 256 + tid;
            myb[i] = -1;
            if (idx < cnt) {
                int e = base + idx;
                int s = src[e], d = dst[e];
                mye[i] = ((unsigned int)s << 16) | (unsigned int)d;   // needs s,d < 65536
                int b = bucket_of(d, N);
                myb[i] = b;
                atomicAdd(&hist[b], 1);
            }
        }
        __syncthreads();
        int p0 = hist[2 * tid], p1 = hist[2 * tid + 1];
        sm[tid] = p0 + p1;
        __syncthreads();
        for (int off = 1; off < 256; off <<= 1) {
            int x = (tid >= off) ? sm[tid - off] : 0;
            __syncthreads();
            sm[tid] += x;
            __syncthreads();
        }
        int excl = sm[tid] - (p0 + p1);
        lstart[2 * tid] = excl;
        lstart[2 * tid + 1] = excl + p0;
        __syncthreads();
        hist[tid] = lstart[tid]; hist[tid + 256] = lstart[tid + 256];
        __syncthreads();
#pragma unroll
        for (int i = 0; i < 16; ++i) {
            if (myb[i] >= 0) {
                int pos = atomicAdd(&hist[myb[i]], 1);
                sorted[pos] = mye[i];
            }
        }
        __syncthreads();
        for (int b = tid; b < NBUCK; b += 256) {
            int c = hist[b] - lstart[b];
            gbase[b] = (c > 0) ? atomicAdd(&bcnt[b], c) : 0;
        }
        __syncthreads();
        for (int idx = tid; idx < cnt; idx += 256) {
            unsigned int v = sorted[idx];
            int b = bucket_of((int)(v & 0xffffu), N);
            ebuf[(size_t)b * BCAP + gbase[b] + (idx - lstart[b])] = v;
        }
        return;
    }
    bb -= nbin;
    if (bb < 128) {    // ---- W1/W2 transpose (64KB each)
        int i = bb * 256 + tid;
        const float* W = (i < 16384) ? W1 : W2;
        unsigned short* Wt = (i < 16384) ? w1t : w2t;
        int idx = i & 16383;
        int n = idx >> 7, k = idx & 127;
        Wt[idx] = f2b(W[k * 128 + n]);
        return;
    }
    bb -= 128;
    {                  // ---- fc1w tiled transpose, 7 x 14 = 98 blocks
        float* tile = (float*)smem;    // 64 x 65 floats = 16640 B
        int n0 = (bb % 7) * 64, k0 = (bb / 7) * 64;
#pragma unroll
        for (int i = 0; i < 16; ++i) {
            int idx = i * 256 + tid;
            int r = idx >> 6, c = idx & 63;
            tile[r * 65 + c] = Wf[(size_t)(k0 + r) * 448 + n0 + c];
        }
        __syncthreads();
#pragma unroll
        for (int i = 0; i < 16; ++i) {
            int idx = i * 256 + tid;
            int c = idx >> 6, r = idx & 63;
            fwt[(size_t)(n0 + c) * 896 + k0 + r] = f2b(tile[r * 65 + c]);
        }
    }
}

// ---------------- CSR pass 2: per-bucket build; bucket base via inline reduction.
__global__ __launch_bounds__(256) void k_build2(const unsigned int* __restrict__ ebuf,
                                                const int* __restrict__ bcnt,
                                                int* __restrict__ offs,
                                                float* __restrict__ dinv,
                                                unsigned short* __restrict__ csr,
                                                int N, int E) {
    __shared__ unsigned short seg[BCAP];
    __shared__ int cnt_l[128];
    __shared__ int scan_l[128];
    __shared__ int curs[128];
    __shared__ int smr[256];
    int b = blockIdx.x, tid = threadIdx.x;
    int part = 0;
    for (int j = tid; j < b; j += 256) part += bcnt[j];
    smr[tid] = part;
    __syncthreads();
    for (int off = 128; off > 0; off >>= 1) {
        if (tid < off) smr[tid] += smr[tid + off];
        __syncthreads();
    }
    int base = smr[0];
    int lo = (int)(((long long)b * N + NBUCK - 1) / NBUCK);
    int cnt = bcnt[b];
    int nrange = (int)(((long long)(b + 1) * N + NBUCK - 1) / NBUCK) - lo;   // <= 98
    if (b == 0 && tid == 0) offs[N] = E;
    if (tid < 128) cnt_l[tid] = 0;
    __syncthreads();
    for (int i = tid; i < cnt; i += 256) {
        unsigned int v = ebuf[(size_t)b * BCAP + i];
        atomicAdd(&cnt_l[(int)(v & 0xffffu) - lo], 1);
    }
    __syncthreads();
    if (tid < 128) scan_l[tid] = cnt_l[tid];
    __syncthreads();
    for (int off = 1; off < 128; off <<= 1) {
        int x = 0;
        if (tid < 128 && tid >= off) x = scan_l[tid - off];
        __syncthreads();
        if (tid < 128) scan_l[tid] += x;
        __syncthreads();
    }
    if (tid < 128) {
        int excl = scan_l[tid] - cnt_l[tid];
        curs[tid] = excl;
        if (tid < nrange) {
            offs[lo + tid] = base + excl;
            dinv[lo + tid] = rsqrtf((float)(cnt_l[tid] + 1));   // +1 = self loop
        }
    }
    __syncthreads();
    for (int i = tid; i < cnt; i += 256) {
        unsigned int v = ebuf[(size_t)b * BCAP + i];
        int d = (int)(v & 0xffffu) - lo;
        int p = atomicAdd(&curs[d], 1);
        seg[p] = (unsigned short)(v >> 16);
    }
    __syncthreads();
    for (int i = tid; i < cnt; i += 256) csr[base + i] = seg[i];
}

// ---------------- MFMA GEMM (fp32 A, inline cvt): out8 = fp8((A @ Bt^T) * rs) ----
__global__ __launch_bounds__(256) void k_gemm_f32a(const float* __restrict__ A,
                                                   const bf16_t* __restrict__ Bt,
                                                   const float* __restrict__ rs,
                                                   unsigned char* __restrict__ out8, int M) {
    __shared__ bf16_t As[64 * 136];
    __shared__ bf16_t Bs[128 * 136];
    int t = threadIdx.x;
    int wave = t >> 6, lane = t & 63, quad = lane >> 4, l16 = lane & 15;
    int r0 = blockIdx.x * 64;
#pragma unroll
    for (int i = 0; i < 4; ++i) {
        int chunk = t + i * 256;
        int row = chunk >> 4, c8 = (chunk & 15) << 3;
        int gr = r0 + row;
        float4 a0 = make_float4(0.f, 0.f, 0.f, 0.f), a1 = a0;
        if (gr < M) {
            a0 = *(const float4*)&A[(size_t)gr * 128 + c8];
            a1 = *(const float4*)&A[(size_t)gr * 128 + c8 + 4];
        }
        *(uint4*)&As[row * 136 + c8] =
            make_uint4(pack2(a0.x, a0.y), pack2(a0.z, a0.w),
                       pack2(a1.x, a1.y), pack2(a1.z, a1.w));
    }
#pragma unroll
    for (int i = 0; i < 8; ++i) {
        int chunk = t + i * 256;
        int row = chunk >> 4, c8 = (chunk & 15) << 3;
        *(uint4*)&Bs[row * 136 + c8] = *(const uint4*)&Bt[row * 128 + c8];
    }
    __syncthreads();

    facc4 acc[8];
#pragma unroll
    for (int nt = 0; nt < 8; ++nt) acc[nt] = (facc4){0.f, 0.f, 0.f, 0.f};
    int arow = (wave << 4) + l16;
#pragma unroll
    for (int ks = 0; ks < 4; ++ks) {
        int kk = ks * 32 + quad * 8;
        bfrag8 af = *(const bfrag8*)&As[arow * 136 + kk];
#pragma unroll
        for (int nt = 0; nt < 8; ++nt) {
            bfrag8 bf = *(const bfrag8*)&Bs[(nt * 16 + l16) * 136 + kk];
            acc[nt] = __builtin_amdgcn_mfma_f32_16x16x32_bf16(af, bf, acc[nt], 0, 0, 0);
        }
    }
    __syncthreads();
    unsigned char* f8t = (unsigned char*)As;   // 64*128 bytes
    int wrow0 = (wave << 4) + quad * 4;
#pragma unroll
    for (int r = 0; r < 4; ++r) {
        int row = wrow0 + r;
        float sc = rs[min(r0 + row, M - 1)];
#pragma unroll
        for (int nt = 0; nt < 8; ++nt)
            f8t[row * 128 + nt * 16 + l16] = fp8_enc(acc[nt][r] * sc);
    }
    __syncthreads();
#pragma unroll
    for (int i = 0; i < 2; ++i) {
        int idx = t + i * 256;              // 512 chunks of 16B
        int row = idx >> 3, cc = (idx & 7) << 4;
        int gr = r0 + row;
        if (gr < M) *(uint4*)&out8[(size_t)gr * 128 + cc] = *(const uint4*)&f8t[row * 128 + cc];
    }
}

// ---------------- MFMA GEMM (bf16 A): out8 = fp8((A @ Bt^T) * rs) ----------------
__global__ __launch_bounds__(256) void k_gemm_nn128(const bf16_t* __restrict__ A,
                                                    const bf16_t* __restrict__ Bt,
                                                    const float* __restrict__ rs,
                                                    unsigned char* __restrict__ out8, int M) {
    __shared__ bf16_t As[64 * 136];
    __shared__ bf16_t Bs[128 * 136];
    int t = threadIdx.x;
    int wave = t >> 6, lane = t & 63, quad = lane >> 4, l16 = lane & 15;
    int r0 = blockIdx.x * 64;
#pragma unroll
    for (int i = 0; i < 4; ++i) {
        int chunk = t + i * 256;
        int row = chunk >> 4, c8 = (chunk & 15) << 3;
        int gr = r0 + row;
        uint4 v = make_uint4(0u, 0u, 0u, 0u);
        if (gr < M) v = *(const uint4*)&A[(size_t)gr * 128 + c8];
        *(uint4*)&As[row * 136 + c8] = v;
    }
#pragma unroll
    for (int i = 0; i < 8; ++i) {
        int chunk = t + i * 256;
        int row = chunk >> 4, c8 = (chunk & 15) << 3;
        *(uint4*)&Bs[row * 136 + c8] = *(const uint4*)&Bt[row * 128 + c8];
    }
    __syncthreads();

    facc4 acc[8];
#pragma unroll
    for (int nt = 0; nt < 8; ++nt) acc[nt] = (facc4){0.f, 0.f, 0.f, 0.f};
    int arow = (wave << 4) + l16;
#pragma unroll
    for (int ks = 0; ks < 4; ++ks) {
        int kk = ks * 32 + quad * 8;
        bfrag8 af = *(const bfrag8*)&As[arow * 136 + kk];
#pragma unroll
        for (int nt = 0; nt < 8; ++nt) {
            bfrag8 bf = *(const bfrag8*)&Bs[(nt * 16 + l16) * 136 + kk];
            acc[nt] = __builtin_amdgcn_mfma_f32_16x16x32_bf16(af, bf, acc[nt], 0, 0, 0);
        }
    }
    __syncthreads();
    unsigned char* f8t = (unsigned char*)As;
    int wrow0 = (wave << 4) + quad * 4;
#pragma unroll
    for (int r = 0; r < 4; ++r) {
        int row = wrow0 + r;
        float sc = rs[min(r0 + row, M - 1)];
#pragma unroll
        for (int nt = 0; nt < 8; ++nt)
            f8t[row * 128 + nt * 16 + l16] = fp8_enc(acc[nt][r] * sc);
    }
    __syncthreads();
#pragma unroll
    for (int i = 0; i < 2; ++i) {
        int idx = t + i * 256;
        int row = idx >> 3, cc = (idx & 7) << 4;
        int gr = r0 + row;
        if (gr < M) *(uint4*)&out8[(size_t)gr * 128 + cc] = *(const uint4*)&f8t[row * 128 + cc];
    }
}

// ---------------- aggregation: wave per node, fp8 gather (128 B/row) ----------------
__global__ __launch_bounds__(256) void k_agg_b(const unsigned short* __restrict__ hx8, // [N][64]
                                               const unsigned short* __restrict__ csr,
                                               const int* __restrict__ offs,
                                               const float* __restrict__ dinv,
                                               const float* __restrict__ bias,
                                               unsigned int* __restrict__ out, int N) {
    int node = blockIdx.x * 4 + (threadIdx.x >> 6);
    int lane = threadIdx.x & 63;
    if (node >= N) return;
    float di = dinv[node];
    f32x2 sf = fp8pair_dec(hx8[(size_t)node * 64 + lane]);
    float acc0 = sf.x, acc1 = sf.y;                   // self term (already *dinv)
    int s0 = offs[node], s1 = offs[node + 1];
    for (int base = s0; base < s1; base += 64) {
        int nloc = min(64, s1 - base);
        int en = 0;
        if (lane < nloc) en = (int)csr[base + lane];
        int j = 0;
        for (; j + 16 <= nloc; j += 16) {
            int sid[16]; unsigned short g[16];
#pragma unroll
            for (int u = 0; u < 16; ++u) sid[u] = __shfl(en, j + u, 64);
#pragma unroll
            for (int u = 0; u < 16; ++u) g[u] = hx8[(size_t)sid[u] * 64 + lane];  // 16 in flight
#pragma unroll
            for (int u = 0; u < 16; ++u) { f32x2 d = fp8pair_dec(g[u]); acc0 += d.x; acc1 += d.y; }
        }
        for (; j + 4 <= nloc; j += 4) {
            int sid[4]; unsigned short g[4];
#pragma unroll
            for (int u = 0; u < 4; ++u) sid[u] = __shfl(en, j + u, 64);
#pragma unroll
            for (int u = 0; u < 4; ++u) g[u] = hx8[(size_t)sid[u] * 64 + lane];
#pragma unroll
            for (int u = 0; u < 4; ++u) { f32x2 d = fp8pair_dec(g[u]); acc0 += d.x; acc1 += d.y; }
        }
        for (; j < nloc; ++j) {
            int srcn = __shfl(en, j, 64);
            f32x2 d = fp8pair_dec(hx8[(size_t)srcn * 64 + lane]);
            acc0 += d.x; acc1 += d.y;
        }
    }
    float2 bb = *(const float2*)&bias[lane * 2];
    float v0 = fmaxf(acc0 * di + bb.x, 0.f);
    float v1 = fmaxf(acc1 * di + bb.y, 0.f);
    out[(size_t)node * 64 + lane] = pack2(v0, v1);
}

// ---------------- entity mean pool (bf16 in/out): wave per row ----------------
__global__ __launch_bounds__(256) void k_pool_b(const unsigned int* __restrict__ h,
                                                const int* __restrict__ ent,
                                                unsigned int* __restrict__ out) {
    int r = blockIdx.x * 4 + (threadIdx.x >> 6);
    int lane = threadIdx.x & 63;
    float a0 = 0.f, a1 = 0.f;
    int cnt = 0;
#pragma unroll
    for (int m = 0; m < 20; ++m) {
        int id = ent[r * 20 + m];
        if (id >= 0) {
            unsigned int q = h[(size_t)id * 64 + lane];
            a0 += blo(q); a1 += bhi(q); cnt++;
        }
    }
    float inv = 1.f / (float)max(cnt, 1);
    out[(size_t)r * 64 + lane] = pack2(a0 * inv, a1 * inv);
}

// ---------------- MLP fc1+fc2 fused (MFMA): 32x64 tiles, 128 thr, no prefetch.
// logacc[row] += sum_col relu(z)*fc2w. bert read fp32 with inline cvt. ----------
__global__ __launch_bounds__(128) void k_mlp1_mfma(const float* __restrict__ bert,  // [B][768] fp32
                                                   const bf16_t* __restrict__ gnnb,
                                                   const bf16_t* __restrict__ fwt,  // [448][896]
                                                   const float* __restrict__ fb,
                                                   const float* __restrict__ w2,   // fc2_w [448]
                                                   float* __restrict__ logacc) {
    __shared__ bf16_t As[32 * 136];
    __shared__ bf16_t Bs[64 * 136];
    int t = threadIdx.x;                 // 0..127
    int wave = t >> 6, lane = t & 63, quad = lane >> 4, l16 = lane & 15;
    int r0 = blockIdx.x * 32, c0 = blockIdx.y * 64;
    facc4 acc[4];
#pragma unroll
    for (int nt = 0; nt < 4; ++nt) acc[nt] = (facc4){0.f, 0.f, 0.f, 0.f};

    for (int ks = 0; ks < 7; ++ks) {
        if (ks < 6) {   // stage A from fp32 bert, inline RNE cvt (8 chunks of 4 floats)
#pragma unroll
            for (int i = 0; i < 8; ++i) {
                int chunk = t + i * 128;           // 1024 chunks: 32 rows x 32
                int row = chunk >> 5, c4 = (chunk & 31) << 2;
                float4 a = *(const float4*)&bert[(size_t)(r0 + row) * 768 + ks * 128 + c4];
                *(uint2*)&As[row * 136 + c4] = make_uint2(pack2(a.x, a.y), pack2(a.z, a.w));
            }
        } else {        // stage A from bf16 gnnb (4 chunks of 8 bf16)
#pragma unroll
            for (int i = 0; i < 4; ++i) {
                int chunk = t + i * 128;           // 512 chunks: 32 rows x 16
                int row = chunk >> 4, c8 = (chunk & 15) << 3;
                *(uint4*)&As[row * 136 + c8] =
                    *(const uint4*)&gnnb[(size_t)(r0 + row) * 128 + c8];
            }
        }
#pragma unroll
        for (int i = 0; i < 8; ++i) {   // stage B: 64 rows x 128 cols bf16
            int chunk = t + i * 128;
            int row = chunk >> 4, c8 = (chunk & 15) << 3;
            *(uint4*)&Bs[row * 136 + c8] =
                *(const uint4*)&fwt[(size_t)(c0 + row) * 896 + ks * 128 + c8];
        }
        __syncthreads();
        int arow = (wave << 4) + l16;
#pragma unroll
        for (int sub = 0; sub < 4; ++sub) {
            int kk = sub * 32 + quad * 8;
            bfrag8 af = *(const bfrag8*)&As[arow * 136 + kk];
#pragma unroll
            for (int nt = 0; nt < 4; ++nt) {
                bfrag8 bf = *(const bfrag8*)&Bs[(nt * 16 + l16) * 136 + kk];
                acc[nt] = __builtin_amdgcn_mfma_f32_16x16x32_bf16(af, bf, acc[nt], 0, 0, 0);
            }
        }
        __syncthreads();
    }
    // epilogue: bias+relu, dot with fc2w slice, reduce over the 16 col-lanes
    int rbase = r0 + (wave << 4) + quad * 4;
    float part[4] = {0.f, 0.f, 0.f, 0.f};
#pragma unroll
    for (int nt = 0; nt < 4; ++nt) {
        int col = c0 + nt * 16 + l16;
        float bb = fb[col];
        float ww = w2[col];
#pragma unroll
        for (int r = 0; r < 4; ++r)
            part[r] += fmaxf(acc[nt][r] + bb, 0.f) * ww;
    }
#pragma unroll
    for (int m = 8; m >= 1; m >>= 1) {
#pragma unroll
        for (int r = 0; r < 4; ++r) part[r] += __shfl_xor(part[r], m, 64);
    }
    if (l16 == 0) {
#pragma unroll
        for (int r = 0; r < 4; ++r) atomicAdd(&logacc[rbase + r], part[r]);
    }
}

// ---------------- sigmoid(logacc + b) ----------------
__global__ void k_sig(const float* __restrict__ logacc, const float* __restrict__ b,
                      float* __restrict__ out, int B) {
    int i = blockIdx.x * 256 + threadIdx.x;
    if (i < B) out[i] = 1.f / (1.f + expf(-(logacc[i] + b[0])));
}

extern "C" void kernel_launch(void* const* d_in, const int* in_sizes, int n_in,
                              void* d_out, int out_size, void* d_ws, size_t ws_size,
                              hipStream_t stream) {
    const float* bert = (const float*)d_in[0];
    const float* x    = (const float*)d_in[1];
    const int*   ei   = (const int*)d_in[2];
    const int*   ent  = (const int*)d_in[3];
    const float* W1   = (const float*)d_in[4];
    const float* b1   = (const float*)d_in[5];
    const float* W2   = (const float*)d_in[6];
    const float* b2   = (const float*)d_in[7];
    const float* fc1w = (const float*)d_in[8];
    const float* fc1b = (const float*)d_in[9];
    const float* fc2w = (const float*)d_in[10];
    const float* fc2b = (const float*)d_in[11];
    float* out = (float*)d_out;

    const int N = in_sizes[1] / 128;   // 50000 (< 65536 required for 16-bit packing)
    const int E = in_sizes[2] / 2;     // 800000
    const int B = in_sizes[0] / 768;   // 4096

    const int* srcv = ei;
    const int* dstv = ei + E;

    char* wsp = (char*)d_ws;
    size_t off = 0;
    auto alloc = [&](size_t bytes) -> void* {
        void* p = wsp + off;
        off += (bytes + 255) & ~(size_t)255;
        return p;
    };
    // bcnt + logacc contiguous -> one memset
    int*   bcnt   = (int*)alloc(NBUCK * 4);               // 2048
    float* logacc = (float*)alloc((size_t)B * 4);         // 16384
    float* dinv   = (float*)alloc((size_t)N * 4);
    int*   offs   = (int*)alloc((size_t)(N + 1) * 4);
    unsigned int*   ebuf  = (unsigned int*)alloc((size_t)NBUCK * BCAP * 4);   // 8 MB
    unsigned short* csr16 = (unsigned short*)alloc((size_t)E * 2);
    bf16_t* w1t   = (bf16_t*)alloc(128 * 128 * 2);
    bf16_t* w2t   = (bf16_t*)alloc(128 * 128 * 2);
    bf16_t* fwt   = (bf16_t*)alloc((size_t)896 * 448 * 2);
    unsigned char* g8buf = (unsigned char*)alloc((size_t)N * 128);   // fp8 h' = (hW)*dinv
    bf16_t* hbuf  = (bf16_t*)alloc((size_t)N * 128 * 2);             // agg out (post-relu)
    bf16_t* gnnb  = (bf16_t*)alloc((size_t)B * 128 * 2);
    (void)ws_size; (void)n_in; (void)out_size;

    hipMemsetAsync(bcnt, 0, 2048 + 16384, stream);

    int nbin = (E + 4095) / 4096;
    int nprep = nbin + 128 + 98;
    k_prepbin<<<nprep, 256, 0, stream>>>(srcv, dstv, bcnt, ebuf, E, N,
                                         W1, (unsigned short*)w1t, W2, (unsigned short*)w2t,
                                         fc1w, (unsigned short*)fwt);
    k_build2<<<NBUCK, 256, 0, stream>>>(ebuf, bcnt, offs, dinv, csr16, N, E);

    int gb = (N + 63) / 64;
    k_gemm_f32a<<<gb, 256, 0, stream>>>(x, w1t, dinv, g8buf, N);
    k_agg_b<<<(N + 3) / 4, 256, 0, stream>>>((const unsigned short*)g8buf, csr16, offs, dinv, b1,
                                             (unsigned int*)hbuf, N);
    k_gemm_nn128<<<gb, 256, 0, stream>>>(hbuf, w2t, dinv, g8buf, N);
    k_agg_b<<<(N + 3) / 4, 256, 0, stream>>>((const unsigned short*)g8buf, csr16, offs, dinv, b2,
                                             (unsigned int*)hbuf, N);
    k_pool_b<<<B / 4, 256, 0, stream>>>((const unsigned int*)hbuf, ent, (unsigned int*)gnnb);
    k_mlp1_mfma<<<dim3(B / 32, 7), 128, 0, stream>>>(bert, gnnb, fwt, fc1b, fc2w, logacc);
    k_sig<<<(B + 255) / 256, 256, 0, stream>>>(logacc, fc2b, out, B);
}